// Round 2
// baseline (86425.934 us; speedup 1.0000x reference)
//
#include <hip/hip_runtime.h>
#include <math.h>

// MGU: f = sigmoid(xf_t + h Wfh^T + bfh); h' = (1-f)h + f*tanh((f*h) Whf^T + bhf + xh_t)
// Phase 1 (parallel): XF = x Wfx^T + bfx + bfh ; XH = x Whx^T + bhx + bhf
// Phase 2 (sequential): persistent cooperative scan, recurrent weights resident
//   in LDS (256 wgs x 8 rows x 2 matrices x 2048 f32 = 33.6 MB aggregate),
//   epoch-flag grid sync between the two dependent matvecs of each step.

#define S_LEN 2048
#define HDIM  2048
#define DDIM  2048
#define NWG   256      // scan workgroups (= CU count; 1 wg/CU due to 144 KiB LDS)
#define ROWS  8        // output rows owned per wg per matvec (256*8 = 2048)
#define SCAN_BLK 256   // 4 waves

// ---------------------------------------------------------------------------
// GEMM: out[s,h] = sum_d x[s,d] * W[h,d] + b1[h] + b2[h]   (biases folded)
// 64x64 tile, K-chunks of 16, 4x4 per thread, f32 vector FMA.
// ---------------------------------------------------------------------------
__global__ __launch_bounds__(256) void xproj_gemm(
    const float* __restrict__ x,
    const float* __restrict__ Wfx, const float* __restrict__ bfx, const float* __restrict__ bfh,
    const float* __restrict__ Whx, const float* __restrict__ bhx, const float* __restrict__ bhf,
    float* __restrict__ XF, float* __restrict__ XH)
{
    const float* W  = blockIdx.z ? Whx : Wfx;
    const float* b1 = blockIdx.z ? bhx : bfx;
    const float* b2 = blockIdx.z ? bhf : bfh;
    float* out      = blockIdx.z ? XH  : XF;

    __shared__ float As[16][64];   // [k][s]
    __shared__ float Bs[16][64];   // [k][h]

    const int tid = threadIdx.x;
    const int s0 = blockIdx.y * 64;
    const int h0 = blockIdx.x * 64;
    const int lr = tid >> 2;          // 0..63 row-in-tile for staging
    const int lk = (tid & 3) << 2;    // 0,4,8,12
    const int ty = tid >> 4;          // 0..15
    const int tx = tid & 15;          // 0..15

    float acc[4][4];
#pragma unroll
    for (int i = 0; i < 4; ++i)
#pragma unroll
        for (int j = 0; j < 4; ++j) acc[i][j] = 0.f;

    for (int k0 = 0; k0 < DDIM; k0 += 16) {
        float4 av = *(const float4*)&x[(size_t)(s0 + lr) * DDIM + k0 + lk];
        float4 bv = *(const float4*)&W[(size_t)(h0 + lr) * DDIM + k0 + lk];
        As[lk + 0][lr] = av.x; As[lk + 1][lr] = av.y; As[lk + 2][lr] = av.z; As[lk + 3][lr] = av.w;
        Bs[lk + 0][lr] = bv.x; Bs[lk + 1][lr] = bv.y; Bs[lk + 2][lr] = bv.z; Bs[lk + 3][lr] = bv.w;
        __syncthreads();
#pragma unroll
        for (int kk = 0; kk < 16; ++kk) {
            float4 a4 = *(const float4*)&As[kk][ty << 2];
            float4 b4 = *(const float4*)&Bs[kk][tx << 2];
            float ar[4] = {a4.x, a4.y, a4.z, a4.w};
            float br[4] = {b4.x, b4.y, b4.z, b4.w};
#pragma unroll
            for (int i = 0; i < 4; ++i)
#pragma unroll
                for (int j = 0; j < 4; ++j)
                    acc[i][j] = fmaf(ar[i], br[j], acc[i][j]);
        }
        __syncthreads();
    }

    float4 bv1 = *(const float4*)&b1[h0 + (tx << 2)];
    float4 bv2 = *(const float4*)&b2[h0 + (tx << 2)];
    float bb[4] = {bv1.x + bv2.x, bv1.y + bv2.y, bv1.z + bv2.z, bv1.w + bv2.w};
#pragma unroll
    for (int i = 0; i < 4; ++i) {
        int s = s0 + (ty << 2) + i;
        float4 o;
        o.x = acc[i][0] + bb[0];
        o.y = acc[i][1] + bb[1];
        o.z = acc[i][2] + bb[2];
        o.w = acc[i][3] + bb[3];
        *(float4*)&out[(size_t)s * HDIM + h0 + (tx << 2)] = o;
    }
}

// ---------------------------------------------------------------------------
// All-lanes epoch-flag wait (each wave polls all NWG flags, 4 per lane).
// On success: acquire fence (invalidates L1 so following plain loads are fresh).
// `bail` becomes 1 after ~1M failed polls (anti-hang: wrong-fast over hung).
// ---------------------------------------------------------------------------
__device__ __forceinline__ void wait_flags(const unsigned* flags, unsigned target,
                                           int lane, int& bail)
{
    if (bail) return;
    int guard = 0;
    for (;;) {
        unsigned ok = 1u;
#pragma unroll
        for (int q = 0; q < NWG / 64; ++q) {
            unsigned v = __hip_atomic_load(&flags[lane + q * 64],
                                           __ATOMIC_RELAXED, __HIP_MEMORY_SCOPE_AGENT);
            ok &= (v >= target) ? 1u : 0u;
        }
        if (__all((int)ok)) break;
        if (++guard > (1 << 20)) { bail = 1; break; }
        __builtin_amdgcn_s_sleep(1);
    }
    __builtin_amdgcn_fence(__ATOMIC_ACQUIRE, "agent");
}

// ---------------------------------------------------------------------------
// Persistent cooperative scan. wg w owns rows [8w, 8w+8) of Wfh and Whf (LDS).
// Per step: wait h(t) -> matvec1 -> publish g slice -> wait g(t) -> matvec2 ->
// publish h slice + y[t].
// ---------------------------------------------------------------------------
__global__ __launch_bounds__(SCAN_BLK) void mgu_scan(
    const float* __restrict__ h0,
    const float* __restrict__ Wfh,
    const float* __restrict__ Whf,
    const float* __restrict__ XF,
    const float* __restrict__ XH,
    float* __restrict__ y,
    float* __restrict__ hfin,
    float* h_buf, float* g_buf,
    unsigned* flags_h, unsigned* flags_g)
{
    extern __shared__ float smem[];
    float* wf    = smem;                     // ROWS*HDIM (Wfh rows)
    float* wh    = wf + ROWS * HDIM;         // ROWS*HDIM (Whf rows)
    float* h_lds = wh + ROWS * HDIM;         // HDIM
    float* g_lds = h_lds + HDIM;             // HDIM

    const int wg   = blockIdx.x;
    const int tid  = threadIdx.x;
    const int lane = tid & 63;
    const int wv   = tid >> 6;               // wave 0..3
    const int base = wg * ROWS;

    // ---- one-time: stage this wg's weight rows into LDS
    for (int i = tid; i < ROWS * HDIM / 4; i += SCAN_BLK) {
        ((float4*)wf)[i] = ((const float4*)(Wfh + (size_t)base * HDIM))[i];
        ((float4*)wh)[i] = ((const float4*)(Whf + (size_t)base * HDIM))[i];
    }
    // ---- init this wg's h slice in the global exchange buffer
    if (tid < ROWS) {
        __hip_atomic_store(&h_buf[base + tid], h0[base + tid],
                           __ATOMIC_RELAXED, __HIP_MEMORY_SCOPE_AGENT);
    }
    __syncthreads();
    if (tid == 0) {
        __builtin_amdgcn_fence(__ATOMIC_RELEASE, "agent");
        __hip_atomic_store(&flags_h[wg], 1u, __ATOMIC_RELEASE, __HIP_MEMORY_SCOPE_AGENT);
    }

    const int r0 = wv * 2, r1 = wv * 2 + 1;  // this wave's rows (of ROWS)
    int bail = 0;

    for (int t = 0; t < S_LEN; ++t) {
        // per-row step constants (issued early, consumed post-reduce)
        float xf0 = XF[(size_t)t * HDIM + base + r0];
        float xf1 = XF[(size_t)t * HDIM + base + r1];
        float xh0 = XH[(size_t)t * HDIM + base + r0];
        float xh1 = XH[(size_t)t * HDIM + base + r1];

        // ---- phase A: all waves wait for h epoch t+1, vector-copy h -> LDS
        wait_flags(flags_h, (unsigned)(t + 1), lane, bail);
        for (int i = tid; i < HDIM / 4; i += SCAN_BLK)
            ((float4*)h_lds)[i] = ((const float4*)h_buf)[i];
        __syncthreads();

        // ---- matvec1: f rows
        float4 a0 = {0, 0, 0, 0}, a1 = {0, 0, 0, 0};
#pragma unroll
        for (int it = 0; it < HDIM / 256; ++it) {
            int j = it * 256 + (lane << 2);
            float4 hv = *(const float4*)&h_lds[j];
            float4 w0 = *(const float4*)&wf[r0 * HDIM + j];
            float4 w1 = *(const float4*)&wf[r1 * HDIM + j];
            a0.x = fmaf(w0.x, hv.x, a0.x); a0.y = fmaf(w0.y, hv.y, a0.y);
            a0.z = fmaf(w0.z, hv.z, a0.z); a0.w = fmaf(w0.w, hv.w, a0.w);
            a1.x = fmaf(w1.x, hv.x, a1.x); a1.y = fmaf(w1.y, hv.y, a1.y);
            a1.z = fmaf(w1.z, hv.z, a1.z); a1.w = fmaf(w1.w, hv.w, a1.w);
        }
        float s0 = (a0.x + a0.y) + (a0.z + a0.w);
        float s1 = (a1.x + a1.y) + (a1.z + a1.w);
#pragma unroll
        for (int m = 32; m >= 1; m >>= 1) {
            s0 += __shfl_xor(s0, m);
            s1 += __shfl_xor(s1, m);
        }
        float f0 = 0.f, f1 = 0.f;
        if (lane == 0) {
            f0 = 1.f / (1.f + expf(-(s0 + xf0)));
            f1 = 1.f / (1.f + expf(-(s1 + xf1)));
            float g0 = f0 * h_lds[base + r0];
            float g1 = f1 * h_lds[base + r1];
            __hip_atomic_store(&g_buf[base + r0], g0, __ATOMIC_RELAXED, __HIP_MEMORY_SCOPE_AGENT);
            __hip_atomic_store(&g_buf[base + r1], g1, __ATOMIC_RELAXED, __HIP_MEMORY_SCOPE_AGENT);
        }
        __syncthreads();
        if (tid == 0) {
            __builtin_amdgcn_fence(__ATOMIC_RELEASE, "agent");
            __hip_atomic_store(&flags_g[wg], (unsigned)(t + 1), __ATOMIC_RELEASE, __HIP_MEMORY_SCOPE_AGENT);
        }

        // ---- phase B: all waves wait for g epoch t+1, vector-copy g -> LDS
        wait_flags(flags_g, (unsigned)(t + 1), lane, bail);
        for (int i = tid; i < HDIM / 4; i += SCAN_BLK)
            ((float4*)g_lds)[i] = ((const float4*)g_buf)[i];
        __syncthreads();

        // ---- matvec2: candidate rows
        a0 = make_float4(0, 0, 0, 0); a1 = make_float4(0, 0, 0, 0);
#pragma unroll
        for (int it = 0; it < HDIM / 256; ++it) {
            int j = it * 256 + (lane << 2);
            float4 gv = *(const float4*)&g_lds[j];
            float4 w0 = *(const float4*)&wh[r0 * HDIM + j];
            float4 w1 = *(const float4*)&wh[r1 * HDIM + j];
            a0.x = fmaf(w0.x, gv.x, a0.x); a0.y = fmaf(w0.y, gv.y, a0.y);
            a0.z = fmaf(w0.z, gv.z, a0.z); a0.w = fmaf(w0.w, gv.w, a0.w);
            a1.x = fmaf(w1.x, gv.x, a1.x); a1.y = fmaf(w1.y, gv.y, a1.y);
            a1.z = fmaf(w1.z, gv.z, a1.z); a1.w = fmaf(w1.w, gv.w, a1.w);
        }
        s0 = (a0.x + a0.y) + (a0.z + a0.w);
        s1 = (a1.x + a1.y) + (a1.z + a1.w);
#pragma unroll
        for (int m = 32; m >= 1; m >>= 1) {
            s0 += __shfl_xor(s0, m);
            s1 += __shfl_xor(s1, m);
        }
        if (lane == 0) {
            float hh0 = tanhf(s0 + xh0);
            float hh1 = tanhf(s1 + xh1);
            float ho0 = h_lds[base + r0];
            float ho1 = h_lds[base + r1];
            float hn0 = ho0 + f0 * (hh0 - ho0);   // (1-f)h + f*hhat
            float hn1 = ho1 + f1 * (hh1 - ho1);
            y[(size_t)t * HDIM + base + r0] = hn0;
            y[(size_t)t * HDIM + base + r1] = hn1;
            __hip_atomic_store(&h_buf[base + r0], hn0, __ATOMIC_RELAXED, __HIP_MEMORY_SCOPE_AGENT);
            __hip_atomic_store(&h_buf[base + r1], hn1, __ATOMIC_RELAXED, __HIP_MEMORY_SCOPE_AGENT);
            if (t == S_LEN - 1) {
                hfin[base + r0] = hn0;
                hfin[base + r1] = hn1;
            }
        }
        __syncthreads();
        if (tid == 0) {
            __builtin_amdgcn_fence(__ATOMIC_RELEASE, "agent");
            __hip_atomic_store(&flags_h[wg], (unsigned)(t + 2), __ATOMIC_RELEASE, __HIP_MEMORY_SCOPE_AGENT);
        }
    }
}

// ---------------------------------------------------------------------------
extern "C" void kernel_launch(void* const* d_in, const int* in_sizes, int n_in,
                              void* d_out, int out_size, void* d_ws, size_t ws_size,
                              hipStream_t stream)
{
    const float* x   = (const float*)d_in[0];
    const float* h0  = (const float*)d_in[1];
    const float* Wfx = (const float*)d_in[2];
    const float* bfx = (const float*)d_in[3];
    const float* Wfh = (const float*)d_in[4];
    const float* bfh = (const float*)d_in[5];
    const float* Whf = (const float*)d_in[6];
    const float* bhf = (const float*)d_in[7];
    const float* Whx = (const float*)d_in[8];
    const float* bhx = (const float*)d_in[9];

    float* y    = (float*)d_out;
    float* hfin = y + (size_t)S_LEN * HDIM;

    // workspace layout
    float* XF         = (float*)d_ws;
    float* XH         = XF + (size_t)S_LEN * HDIM;
    float* h_buf      = XH + (size_t)S_LEN * HDIM;
    float* g_buf      = h_buf + HDIM;
    unsigned* flags_h = (unsigned*)(g_buf + HDIM);
    unsigned* flags_g = flags_h + NWG;

    // epoch flags must start at 0 every call (ws is re-poisoned each launch)
    hipMemsetAsync(flags_h, 0, 2 * NWG * sizeof(unsigned), stream);

    // phase 1: input projections (biases folded: XF += bfx+bfh, XH += bhx+bhf)
    dim3 gg(HDIM / 64, S_LEN / 64, 2);
    xproj_gemm<<<gg, 256, 0, stream>>>(x, Wfx, bfx, bfh, Whx, bhx, bhf, XF, XH);

    // phase 2: cooperative persistent scan (144 KiB dynamic LDS -> 1 wg/CU)
    const int smem_bytes = (2 * ROWS * HDIM + 2 * HDIM) * (int)sizeof(float); // 147456
    hipFuncSetAttribute((const void*)mgu_scan,
                        hipFuncAttributeMaxDynamicSharedMemorySize, smem_bytes);

    void* args[] = {(void*)&h0, (void*)&Wfh, (void*)&Whf, (void*)&XF, (void*)&XH,
                    (void*)&y, (void*)&hfin, (void*)&h_buf, (void*)&g_buf,
                    (void*)&flags_h, (void*)&flags_g};
    hipError_t err = hipLaunchCooperativeKernel((void*)mgu_scan, dim3(NWG), dim3(SCAN_BLK),
                                                args, (unsigned)smem_bytes, stream);
    if (err != hipSuccess) {
        // fallback: plain launch (grid == CU count, 1 wg/CU -> co-resident;
        // wait_flags' bail guard prevents a hard hang if co-residency fails)
        mgu_scan<<<dim3(NWG), dim3(SCAN_BLK), smem_bytes, stream>>>(
            h0, Wfh, Whf, XF, XH, y, hfin, h_buf, g_buf, flags_h, flags_g);
    }
}

// Round 3
// 18287.268 us; speedup vs baseline: 4.7260x; 4.7260x over previous
//
#include <hip/hip_runtime.h>
#include <math.h>

// MGU: f = sigmoid(xf_t + h Wfh^T + bfh); h' = (1-f)h + f*tanh((f*h) Whf^T + bhf + xh_t)
// Phase 1 (parallel): XF = x Wfx^T + bfx + bfh ; XH = x Whx^T + bhx + bhf
// Phase 2 (sequential): persistent cooperative scan, recurrent weights resident
//   in LDS. Cross-wg exchange via SELF-VALIDATING TAGGED WORDS:
//   each element is a 64-bit relaxed agent-scope atomic (epoch<<32 | f32 bits).
//   NO acquire/release fences (on gfx950 an agent fence = full per-XCD L2
//   invalidate/writeback -> that was 41 us/step in round 2). Tag+payload in one
//   atomic word needs no ordering at all.

#define S_LEN 2048
#define HDIM  2048
#define DDIM  2048
#define NWG   256      // scan workgroups (= CU count; 1 wg/CU due to 144 KiB LDS)
#define ROWS  8        // output rows owned per wg (256*8 = 2048)
#define SCAN_BLK 256   // 4 waves
#define QELEM (HDIM / SCAN_BLK)   // 8 tagged elements gathered per thread

typedef unsigned long long ull;

// ---------------------------------------------------------------------------
// GEMM: out[s,h] = sum_d x[s,d] * W[h,d] + b1[h] + b2[h]   (biases folded)
// 64x64 tile, K-chunks of 16, 4x4 per thread, f32 vector FMA.
// ---------------------------------------------------------------------------
__global__ __launch_bounds__(256) void xproj_gemm(
    const float* __restrict__ x,
    const float* __restrict__ Wfx, const float* __restrict__ bfx, const float* __restrict__ bfh,
    const float* __restrict__ Whx, const float* __restrict__ bhx, const float* __restrict__ bhf,
    float* __restrict__ XF, float* __restrict__ XH)
{
    const float* W  = blockIdx.z ? Whx : Wfx;
    const float* b1 = blockIdx.z ? bhx : bfx;
    const float* b2 = blockIdx.z ? bhf : bfh;
    float* out      = blockIdx.z ? XH  : XF;

    __shared__ float As[16][64];   // [k][s]
    __shared__ float Bs[16][64];   // [k][h]

    const int tid = threadIdx.x;
    const int s0 = blockIdx.y * 64;
    const int h0 = blockIdx.x * 64;
    const int lr = tid >> 2;          // 0..63 row-in-tile for staging
    const int lk = (tid & 3) << 2;    // 0,4,8,12
    const int ty = tid >> 4;          // 0..15
    const int tx = tid & 15;          // 0..15

    float acc[4][4];
#pragma unroll
    for (int i = 0; i < 4; ++i)
#pragma unroll
        for (int j = 0; j < 4; ++j) acc[i][j] = 0.f;

    for (int k0 = 0; k0 < DDIM; k0 += 16) {
        float4 av = *(const float4*)&x[(size_t)(s0 + lr) * DDIM + k0 + lk];
        float4 bv = *(const float4*)&W[(size_t)(h0 + lr) * DDIM + k0 + lk];
        As[lk + 0][lr] = av.x; As[lk + 1][lr] = av.y; As[lk + 2][lr] = av.z; As[lk + 3][lr] = av.w;
        Bs[lk + 0][lr] = bv.x; Bs[lk + 1][lr] = bv.y; Bs[lk + 2][lr] = bv.z; Bs[lk + 3][lr] = bv.w;
        __syncthreads();
#pragma unroll
        for (int kk = 0; kk < 16; ++kk) {
            float4 a4 = *(const float4*)&As[kk][ty << 2];
            float4 b4 = *(const float4*)&Bs[kk][tx << 2];
            float ar[4] = {a4.x, a4.y, a4.z, a4.w};
            float br[4] = {b4.x, b4.y, b4.z, b4.w};
#pragma unroll
            for (int i = 0; i < 4; ++i)
#pragma unroll
                for (int j = 0; j < 4; ++j)
                    acc[i][j] = fmaf(ar[i], br[j], acc[i][j]);
        }
        __syncthreads();
    }

    float4 bv1 = *(const float4*)&b1[h0 + (tx << 2)];
    float4 bv2 = *(const float4*)&b2[h0 + (tx << 2)];
    float bb[4] = {bv1.x + bv2.x, bv1.y + bv2.y, bv1.z + bv2.z, bv1.w + bv2.w};
#pragma unroll
    for (int i = 0; i < 4; ++i) {
        int s = s0 + (ty << 2) + i;
        float4 o;
        o.x = acc[i][0] + bb[0];
        o.y = acc[i][1] + bb[1];
        o.z = acc[i][2] + bb[2];
        o.w = acc[i][3] + bb[3];
        *(float4*)&out[(size_t)s * HDIM + h0 + (tx << 2)] = o;
    }
}

// ---------------------------------------------------------------------------
// Tagged publish / gather (NO fences; relaxed agent atomics only).
// ---------------------------------------------------------------------------
__device__ __forceinline__ void publish_tagged(ull* buf, int idx, unsigned epoch, float v)
{
    ull w = ((ull)epoch << 32) | (ull)__float_as_uint(v);
    __hip_atomic_store(&buf[idx], w, __ATOMIC_RELAXED, __HIP_MEMORY_SCOPE_AGENT);
}

// Gather all HDIM elements with tag == target into lds[]. Each thread owns
// QELEM strided elements; done-mask keeps all its loads in flight per round.
// Ends with __syncthreads(). `bail` guard prevents a hard hang (wrong-fast).
__device__ __forceinline__ void gather_tagged(const ull* buf, unsigned target,
                                              float* lds, int tid, int& bail)
{
    unsigned done = bail ? 0xffu : 0u;
    int guard = 0;
    while (done != 0xffu) {
#pragma unroll
        for (int q = 0; q < QELEM; ++q) {
            if (!((done >> q) & 1u)) {
                ull w = __hip_atomic_load(&buf[tid + q * SCAN_BLK],
                                          __ATOMIC_RELAXED, __HIP_MEMORY_SCOPE_AGENT);
                if ((unsigned)(w >> 32) == target) {
                    lds[tid + q * SCAN_BLK] = __uint_as_float((unsigned)w);
                    done |= (1u << q);
                }
            }
        }
        if (done != 0xffu) {
            if (++guard > (1 << 20)) { bail = 1; break; }
            __builtin_amdgcn_s_sleep(1);
        }
    }
    __syncthreads();
}

// ---------------------------------------------------------------------------
// Persistent cooperative scan. wg w owns rows [8w, 8w+8) of Wfh and Whf (LDS).
// Per step: gather h(t) -> matvec1 -> publish g(t) -> gather g(t) -> matvec2
// -> publish h(t+1) + y[t].  Epochs: h0 tag=1; step t gathers tag t+1,
// publishes g tag t+1 and h tag t+2.
// ---------------------------------------------------------------------------
__global__ __launch_bounds__(SCAN_BLK) void mgu_scan(
    const float* __restrict__ h0,
    const float* __restrict__ Wfh,
    const float* __restrict__ Whf,
    const float* __restrict__ XF,
    const float* __restrict__ XH,
    float* __restrict__ y,
    float* __restrict__ hfin,
    ull* h_buf, ull* g_buf)
{
    extern __shared__ float smem[];
    float* wf    = smem;                     // ROWS*HDIM (Wfh rows)
    float* wh    = wf + ROWS * HDIM;         // ROWS*HDIM (Whf rows)
    float* h_lds = wh + ROWS * HDIM;         // HDIM
    float* g_lds = h_lds + HDIM;             // HDIM

    const int wg   = blockIdx.x;
    const int tid  = threadIdx.x;
    const int lane = tid & 63;
    const int wv   = tid >> 6;               // wave 0..3
    const int base = wg * ROWS;

    // ---- one-time: stage this wg's weight rows into LDS
    for (int i = tid; i < ROWS * HDIM / 4; i += SCAN_BLK) {
        ((float4*)wf)[i] = ((const float4*)(Wfh + (size_t)base * HDIM))[i];
        ((float4*)wh)[i] = ((const float4*)(Whf + (size_t)base * HDIM))[i];
    }
    // ---- publish this wg's h0 slice, tag 1
    if (tid < ROWS)
        publish_tagged(h_buf, base + tid, 1u, h0[base + tid]);
    __syncthreads();

    const int r0 = wv * 2, r1 = wv * 2 + 1;  // this wave's rows (of ROWS)
    int bail = 0;

    for (int t = 0; t < S_LEN; ++t) {
        // per-row step constants (issued before the gather wait -> overlapped)
        float xf0 = XF[(size_t)t * HDIM + base + r0];
        float xf1 = XF[(size_t)t * HDIM + base + r1];
        float xh0 = XH[(size_t)t * HDIM + base + r0];
        float xh1 = XH[(size_t)t * HDIM + base + r1];

        // ---- phase A: gather h(t) (tag t+1) into LDS
        gather_tagged(h_buf, (unsigned)(t + 1), h_lds, tid, bail);

        // ---- matvec1: f rows
        float4 a0 = {0, 0, 0, 0}, a1 = {0, 0, 0, 0};
#pragma unroll
        for (int it = 0; it < HDIM / 256; ++it) {
            int j = it * 256 + (lane << 2);
            float4 hv = *(const float4*)&h_lds[j];
            float4 w0 = *(const float4*)&wf[r0 * HDIM + j];
            float4 w1 = *(const float4*)&wf[r1 * HDIM + j];
            a0.x = fmaf(w0.x, hv.x, a0.x); a0.y = fmaf(w0.y, hv.y, a0.y);
            a0.z = fmaf(w0.z, hv.z, a0.z); a0.w = fmaf(w0.w, hv.w, a0.w);
            a1.x = fmaf(w1.x, hv.x, a1.x); a1.y = fmaf(w1.y, hv.y, a1.y);
            a1.z = fmaf(w1.z, hv.z, a1.z); a1.w = fmaf(w1.w, hv.w, a1.w);
        }
        float s0 = (a0.x + a0.y) + (a0.z + a0.w);
        float s1 = (a1.x + a1.y) + (a1.z + a1.w);
#pragma unroll
        for (int m = 32; m >= 1; m >>= 1) {
            s0 += __shfl_xor(s0, m);
            s1 += __shfl_xor(s1, m);
        }
        float f0 = 0.f, f1 = 0.f, ho0 = 0.f, ho1 = 0.f;
        if (lane == 0) {
            f0 = 1.f / (1.f + expf(-(s0 + xf0)));
            f1 = 1.f / (1.f + expf(-(s1 + xf1)));
            ho0 = h_lds[base + r0];              // cache h_old in registers:
            ho1 = h_lds[base + r1];              // no reader of h_lds after this
            publish_tagged(g_buf, base + r0, (unsigned)(t + 1), f0 * ho0);
            publish_tagged(g_buf, base + r1, (unsigned)(t + 1), f1 * ho1);
        }

        // ---- phase B: gather g(t) (tag t+1) into LDS
        gather_tagged(g_buf, (unsigned)(t + 1), g_lds, tid, bail);

        // ---- matvec2: candidate rows
        a0 = make_float4(0, 0, 0, 0); a1 = make_float4(0, 0, 0, 0);
#pragma unroll
        for (int it = 0; it < HDIM / 256; ++it) {
            int j = it * 256 + (lane << 2);
            float4 gv = *(const float4*)&g_lds[j];
            float4 w0 = *(const float4*)&wh[r0 * HDIM + j];
            float4 w1 = *(const float4*)&wh[r1 * HDIM + j];
            a0.x = fmaf(w0.x, gv.x, a0.x); a0.y = fmaf(w0.y, gv.y, a0.y);
            a0.z = fmaf(w0.z, gv.z, a0.z); a0.w = fmaf(w0.w, gv.w, a0.w);
            a1.x = fmaf(w1.x, gv.x, a1.x); a1.y = fmaf(w1.y, gv.y, a1.y);
            a1.z = fmaf(w1.z, gv.z, a1.z); a1.w = fmaf(w1.w, gv.w, a1.w);
        }
        s0 = (a0.x + a0.y) + (a0.z + a0.w);
        s1 = (a1.x + a1.y) + (a1.z + a1.w);
#pragma unroll
        for (int m = 32; m >= 1; m >>= 1) {
            s0 += __shfl_xor(s0, m);
            s1 += __shfl_xor(s1, m);
        }
        if (lane == 0) {
            float hh0 = tanhf(s0 + xh0);
            float hh1 = tanhf(s1 + xh1);
            float hn0 = ho0 + f0 * (hh0 - ho0);   // (1-f)h + f*hhat
            float hn1 = ho1 + f1 * (hh1 - ho1);
            y[(size_t)t * HDIM + base + r0] = hn0;
            y[(size_t)t * HDIM + base + r1] = hn1;
            publish_tagged(h_buf, base + r0, (unsigned)(t + 2), hn0);
            publish_tagged(h_buf, base + r1, (unsigned)(t + 2), hn1);
            if (t == S_LEN - 1) {
                hfin[base + r0] = hn0;
                hfin[base + r1] = hn1;
            }
        }
        // no end-of-loop barrier needed: h_lds/g_lds writers (the gathers)
        // each end with __syncthreads(), and h_old is register-cached.
    }
}

// ---------------------------------------------------------------------------
extern "C" void kernel_launch(void* const* d_in, const int* in_sizes, int n_in,
                              void* d_out, int out_size, void* d_ws, size_t ws_size,
                              hipStream_t stream)
{
    const float* x   = (const float*)d_in[0];
    const float* h0  = (const float*)d_in[1];
    const float* Wfx = (const float*)d_in[2];
    const float* bfx = (const float*)d_in[3];
    const float* Wfh = (const float*)d_in[4];
    const float* bfh = (const float*)d_in[5];
    const float* Whf = (const float*)d_in[6];
    const float* bhf = (const float*)d_in[7];
    const float* Whx = (const float*)d_in[8];
    const float* bhx = (const float*)d_in[9];

    float* y    = (float*)d_out;
    float* hfin = y + (size_t)S_LEN * HDIM;

    // workspace layout (tags self-validate vs 0xAA poison -> no memset needed)
    float* XF  = (float*)d_ws;
    float* XH  = XF + (size_t)S_LEN * HDIM;
    ull* h_buf = (ull*)(XH + (size_t)S_LEN * HDIM);
    ull* g_buf = h_buf + HDIM;

    // phase 1: input projections (biases folded: XF += bfx+bfh, XH += bhx+bhf)
    dim3 gg(HDIM / 64, S_LEN / 64, 2);
    xproj_gemm<<<gg, 256, 0, stream>>>(x, Wfx, bfx, bfh, Whx, bhx, bhf, XF, XH);

    // phase 2: cooperative persistent scan (144 KiB dynamic LDS -> 1 wg/CU)
    const int smem_bytes = (2 * ROWS * HDIM + 2 * HDIM) * (int)sizeof(float); // 147456
    hipFuncSetAttribute((const void*)mgu_scan,
                        hipFuncAttributeMaxDynamicSharedMemorySize, smem_bytes);

    void* args[] = {(void*)&h0, (void*)&Wfh, (void*)&Whf, (void*)&XF, (void*)&XH,
                    (void*)&y, (void*)&hfin, (void*)&h_buf, (void*)&g_buf};
    hipError_t err = hipLaunchCooperativeKernel((void*)mgu_scan, dim3(NWG), dim3(SCAN_BLK),
                                                args, (unsigned)smem_bytes, stream);
    if (err != hipSuccess) {
        // fallback: plain launch (grid == CU count, 1 wg/CU -> co-resident;
        // gather's bail guard prevents a hard hang if co-residency fails)
        mgu_scan<<<dim3(NWG), dim3(SCAN_BLK), smem_bytes, stream>>>(
            h0, Wfh, Whf, XF, XH, y, hfin, h_buf, g_buf);
    }
}